// Round 1
// 260.438 us; speedup vs baseline: 1.0543x; 1.0543x over previous
//
#include <hip/hip_runtime.h>
#include <math.h>

// Problem constants
#define LEN 18360              // LEN_Q == LEN_V
#define M_ROWS (2 * LEN)       // 36720 rows (B * LEN)
#define NTASK (16 * LEN)       // B * HEADS * LEN tasks = 293760

typedef unsigned short u16;
typedef __attribute__((ext_vector_type(8))) short bf16x8;
typedef __attribute__((ext_vector_type(4))) float f32x4;
typedef __attribute__((ext_vector_type(2))) float f32x2;

__device__ __forceinline__ u16 f2bf(float f) {  // RNE fp32 -> bf16
  unsigned u = __float_as_uint(f);
  return (u16)((u + 0x7fffu + ((u >> 16) & 1u)) >> 16);
}
__device__ __forceinline__ void async_cp16(const void* g, void* l) {
  __builtin_amdgcn_global_load_lds(
      (const __attribute__((address_space(1))) unsigned*)g,
      (__attribute__((address_space(3))) unsigned*)l, 16, 0, 0);
}
// bf16 pair (packed in u32) -> packed f32x2 {lo, hi}
__device__ __forceinline__ f32x2 bfpair(unsigned u) {
  return (f32x2){__uint_as_float(u << 16), __uint_as_float(u & 0xffff0000u)};
}

// ---------------------------------------------------------------------------
// Batched bf16 MFMA GEMM: up to two independent sub-GEMMs in one launch
// (block-id range select; all block-uniform branching). Each sub-GEMM:
// C[M_ROWS, N] = A[M_ROWS,256] * Bt[N,256]^T + bias[N].
// 128x128 tile, 4 waves, wave = 64x64 via 4x4 frags of 16x16x32 bf16 MFMA,
// operands swapped (computes C^T) so a lane's 4 acc elems = 4 consecutive
// C-columns. Modes: 0 = fp32 row-major, 1 = bf16 vproj layout
// [((b*8+h)*LEN+lv)*32+d], 2 = bf16 row-major.
// ---------------------------------------------------------------------------
__global__ __launch_bounds__(256) void gemm_mfma_k(
    const u16* __restrict__ A0, const u16* __restrict__ Bt0,
    const float* __restrict__ bias0, void* __restrict__ C0, int N0, int nt0,
    int mode0, int split, const u16* __restrict__ A1,
    const u16* __restrict__ Bt1, const float* __restrict__ bias1,
    void* __restrict__ C1, int N1, int nt1, int mode1) {
  __shared__ u16 A_lds[8 * 512];  // 8 subtiles (16m x 32k), frag-contiguous
  __shared__ u16 B_lds[8 * 512];

  int bid = (int)blockIdx.x;
  const u16* A;
  const u16* Bt;
  const float* bias;
  void* Cv;
  int N, nt, mode;
  if (bid < split) {
    A = A0; Bt = Bt0; bias = bias0; Cv = C0; N = N0; nt = nt0; mode = mode0;
  } else {
    bid -= split;
    A = A1; Bt = Bt1; bias = bias1; Cv = C1; N = N1; nt = nt1; mode = mode1;
  }
  const int n0 = (bid % nt) << 7;
  const int m0 = (bid / nt) << 7;

  const int tid = threadIdx.x;
  const int w = tid >> 6;
  const int lane = tid & 63;
  const int wm = w & 1, wn = w >> 1;
  const int mr = lane & 15;
  const int kq = (lane >> 4) * 8;

  f32x4 acc[4][4];
#pragma unroll
  for (int i = 0; i < 4; i++)
#pragma unroll
    for (int j = 0; j < 4; j++) acc[i][j] = (f32x4){0.f, 0.f, 0.f, 0.f};

  for (int k0 = 0; k0 < 256; k0 += 32) {
    __syncthreads();
#pragma unroll
    for (int t = 0; t < 2; t++) {
      const int st = 2 * w + t;
      const int ga = min(m0 + st * 16 + mr, M_ROWS - 1);
      async_cp16(A + (size_t)ga * 256 + k0 + kq, &A_lds[st * 512]);
      const int gb = n0 + st * 16 + mr;  // always < N (N multiple of 128)
      async_cp16(Bt + (size_t)gb * 256 + k0 + kq, &B_lds[st * 512]);
    }
    __syncthreads();

    bf16x8 af[4], bf[4];
#pragma unroll
    for (int i = 0; i < 4; i++)
      af[i] = *(const bf16x8*)&A_lds[(wm * 4 + i) * 512 + lane * 8];
#pragma unroll
    for (int j = 0; j < 4; j++)
      bf[j] = *(const bf16x8*)&B_lds[(wn * 4 + j) * 512 + lane * 8];
#pragma unroll
    for (int i = 0; i < 4; i++)
#pragma unroll
      for (int j = 0; j < 4; j++)
        acc[i][j] = __builtin_amdgcn_mfma_f32_16x16x32_bf16(bf[j], af[i],
                                                            acc[i][j], 0, 0, 0);
  }

#pragma unroll
  for (int i = 0; i < 4; i++) {
    const int row = m0 + wm * 64 + i * 16 + mr;
    if (row >= M_ROWS) continue;
#pragma unroll
    for (int j = 0; j < 4; j++) {
      const int col = n0 + wn * 64 + j * 16 + (lane >> 4) * 4;
      const float4 b4 = *(const float4*)(bias + col);
      float4 o;
      o.x = acc[i][j][0] + b4.x;
      o.y = acc[i][j][1] + b4.y;
      o.z = acc[i][j][2] + b4.z;
      o.w = acc[i][j][3] + b4.w;
      if (mode == 0) {
        *(float4*)((float*)Cv + (size_t)row * N + col) = o;
      } else if (mode == 1) {
        const int b = row >= LEN;
        const int lv = row - b * LEN;
        const int h = col >> 5, d = col & 31;
        uint2 p;
        p.x = (unsigned)f2bf(o.x) | ((unsigned)f2bf(o.y) << 16);
        p.y = (unsigned)f2bf(o.z) | ((unsigned)f2bf(o.w) << 16);
        *(uint2*)((u16*)Cv + ((size_t)((b * 8 + h) * LEN + lv)) * 32 + d) = p;
      } else {
        uint2 p;
        p.x = (unsigned)f2bf(o.x) | ((unsigned)f2bf(o.y) << 16);
        p.y = (unsigned)f2bf(o.z) | ((unsigned)f2bf(o.w) << 16);
        *(uint2*)((u16*)Cv + (size_t)row * N + col) = p;
      }
    }
  }
}

// ---------------------------------------------------------------------------
__global__ __launch_bounds__(256) void cast_qv_k(const float* __restrict__ q,
                                                 const float* __restrict__ v,
                                                 u16* __restrict__ qb,
                                                 u16* __restrict__ vb) {
  const size_t i = ((size_t)blockIdx.x * 256 + threadIdx.x) * 4;
  float4 a = *(const float4*)(q + i);
  uint2 p;
  p.x = (unsigned)f2bf(a.x) | ((unsigned)f2bf(a.y) << 16);
  p.y = (unsigned)f2bf(a.z) | ((unsigned)f2bf(a.w) << 16);
  *(uint2*)&qb[i] = p;
  float4 c = *(const float4*)(v + i);
  p.x = (unsigned)f2bf(c.x) | ((unsigned)f2bf(c.y) << 16);
  p.y = (unsigned)f2bf(c.z) | ((unsigned)f2bf(c.w) << 16);
  *(uint2*)&vb[i] = p;
}

// ---------------------------------------------------------------------------
// Weight transpose+cast into [n][k] bf16, plus bias concat (sob||ab -> 384).
// sa_t is the concatenated [384][256] weight for the fused off+aw GEMM.
// ---------------------------------------------------------------------------
__global__ __launch_bounds__(256) void wcast_k(
    const float* __restrict__ vpk, const float* __restrict__ sok,
    const float* __restrict__ ak, const float* __restrict__ ok,
    const float* __restrict__ sob, const float* __restrict__ ab,
    u16* __restrict__ vpk_t, u16* __restrict__ sa_t, u16* __restrict__ ok_t,
    float* __restrict__ bias_cat) {
  const int gid = blockIdx.x * 256 + threadIdx.x;
  if (gid < 65536) {
    const int d = gid, n = d >> 8, k = d & 255;
    vpk_t[d] = f2bf(vpk[k * 256 + n]);
  } else if (gid < 131072) {
    const int d = gid - 65536, n = d >> 8, k = d & 255;
    sa_t[d] = f2bf(sok[k * 256 + n]);
  } else if (gid < 163840) {
    const int d = gid - 131072, n = d >> 8, k = d & 255;  // n < 128
    sa_t[65536 + d] = f2bf(ak[k * 128 + n]);
  } else if (gid < 229376) {
    const int d = gid - 163840, n = d >> 8, k = d & 255;
    ok_t[d] = f2bf(ok[k * 256 + n]);
  } else if (gid < 229760) {
    const int d = gid - 229376;
    bias_cat[d] = (d < 256) ? sob[d] : ab[d - 256];
  }
}

// ---------------------------------------------------------------------------
// Sampler. v is bf16 [b][h][LEN][32]; offaw bf16 [b*LEN][384] (cols 0..255 =
// offsets, 256..383 = logits). x out bf16.
// 32 tasks/block. Phase 1: 2 reps x (16 tasks x 16 lanes) computes the 64
// (byte-offset, weight) corner pairs per task into LDS. Phase 2: 8 lanes/task
// (c2 = corner-pair 0/1, dq = 16B channel chunk 0..3); each lane gathers
// dwordx4 (8 bf16 channels) per corner-sample, accumulates with packed
// v_pk_fma_f32, then one shfl_xor(4) merge and a 16B store from c2==0 lanes.
// meta layout: flat [c*552 + t*17 + s] int2 (552%16==8, 17%16==1 in 8B
// bank-pairs) -> phase-2 read banks = 8*c2 + t + s: conflict-free.
// vb base is wave-uniform (8 consecutive tasks, LEN%8==0) -> readfirstlane
// puts it in SGPRs: global_load with saddr + 32-bit voffset.
// ---------------------------------------------------------------------------
__global__ __launch_bounds__(256) void sampler_k(
    const u16* __restrict__ v,      // bf16 [b][h][LEN][32]
    const u16* __restrict__ offaw,  // bf16 [b*LEN][384]
    const float* __restrict__ refp, // fp32 [b*LEN][4][2]
    u16* __restrict__ xb)           // bf16 [b*LEN][256]
{
  __shared__ int2 meta[4 * 552];
  const int tid = threadIdx.x;

  // ---------------- phase 1 ----------------
#pragma unroll
  for (int rep = 0; rep < 2; rep++) {
    const int t = rep * 16 + (tid >> 4);
    const int s = tid & 15;
    const int l = s >> 2;

    const int task = (blockIdx.x << 5) + t;
    const int q = task % LEN;
    const int bh = task / LEN;
    const int h = bh & 7;
    const int b = bh >> 3;
    const size_t qrow = (size_t)(b * LEN + q);
    const u16* rowp = offaw + qrow * 384;

    const float logit = __uint_as_float((unsigned)rowp[256 + h * 16 + s] << 16);
    float mx = logit;
#pragma unroll
    for (int m = 1; m < 16; m <<= 1) mx = fmaxf(mx, __shfl_xor(mx, m, 16));
    const float e = __expf(logit - mx);
    float ssum = e;
#pragma unroll
    for (int m = 1; m < 16; m <<= 1) ssum += __shfl_xor(ssum, m, 16);
    const float wsm = e / ssum;

    // level geometry via shifts: W=144>>l, H=96>>l, ST=18432-(18432>>(2l))
    const int W = 144 >> l, H = 96 >> l;
    const int ST = 18432 - (18432 >> (2 * l));
    const float2 rp = ((const float2*)(refp + qrow * 8))[l];
    const unsigned upair = ((const unsigned*)(rowp + h * 32))[s];
    const float ox = __uint_as_float(upair << 16);
    const float oy = __uint_as_float(upair & 0xffff0000u);
    const float X = rp.x * (float)W + ox - 0.5f;
    const float Y = rp.y * (float)H + oy - 0.5f;
    const float fx = floorf(X), fy = floorf(Y);
    const int x0 = (int)fx, y0 = (int)fy;
    const float dx = X - fx, dy = Y - fy;
    const float ux = 1.f - dx, uy = 1.f - dy;
    const bool bx0 = (unsigned)x0 < (unsigned)W;
    const bool bx1 = (unsigned)(x0 + 1) < (unsigned)W;
    const bool by0 = (unsigned)y0 < (unsigned)H;
    const bool by1 = (unsigned)(y0 + 1) < (unsigned)H;
    const int xc0 = min(max(x0, 0), W - 1);
    const int xc1 = min(max(x0 + 1, 0), W - 1);
    const int yc0 = min(max(y0, 0), H - 1);
    const int yc1 = min(max(y0 + 1, 0), H - 1);
    const float w00 = (bx0 & by0) ? wsm * ux * uy : 0.f;
    const float w10 = (bx1 & by0) ? wsm * dx * uy : 0.f;
    const float w01 = (bx0 & by1) ? wsm * ux * dy : 0.f;
    const float w11 = (bx1 & by1) ? wsm * dx * dy : 0.f;

    // byte offsets into a bf16 row-plane: 64 B per spatial position
    int2* mt = &meta[t * 17 + s];
    mt[0 * 552] = make_int2((ST + yc0 * W + xc0) << 6, __float_as_int(w00));
    mt[1 * 552] = make_int2((ST + yc0 * W + xc1) << 6, __float_as_int(w10));
    mt[2 * 552] = make_int2((ST + yc1 * W + xc0) << 6, __float_as_int(w01));
    mt[3 * 552] = make_int2((ST + yc1 * W + xc1) << 6, __float_as_int(w11));
  }
  __syncthreads();

  // ---------------- phase 2 ----------------
  const int u = tid >> 3;         // task slot 0..31
  const int c2 = (tid >> 2) & 1;  // corner pair: {0,2} or {1,3}
  const int dq = tid & 3;         // 16B channel chunk

  const int task = (blockIdx.x << 5) + u;
  const int q = task % LEN;
  const int bh = task / LEN;
  const int h = bh & 7;
  const int b = bh >> 3;
  const size_t qrow = (size_t)(b * LEN + q);
  // wave-uniform (b,h) plane base -> SGPR
  const char* vb = (const char*)v +
                   (size_t)__builtin_amdgcn_readfirstlane(bh) * (LEN * 64);
  const int dqo = dq << 4;

  f32x2 a0 = {0.f, 0.f}, a1 = {0.f, 0.f}, a2 = {0.f, 0.f}, a3 = {0.f, 0.f};
#pragma unroll
  for (int ci = 0; ci < 2; ci++) {
    const int2* mrow = &meta[(c2 + 2 * ci) * 552 + u * 17];
#pragma unroll
    for (int s = 0; s < 16; s++) {
      const int2 m2 = mrow[s];
      const float wgt = __int_as_float(m2.y);
      const f32x2 wp = {wgt, wgt};
      const uint4 pv = *(const uint4*)(vb + (unsigned)m2.x + dqo);
#if __has_builtin(__builtin_elementwise_fma)
      a0 = __builtin_elementwise_fma(wp, bfpair(pv.x), a0);
      a1 = __builtin_elementwise_fma(wp, bfpair(pv.y), a1);
      a2 = __builtin_elementwise_fma(wp, bfpair(pv.z), a2);
      a3 = __builtin_elementwise_fma(wp, bfpair(pv.w), a3);
#else
      a0 = wp * bfpair(pv.x) + a0;
      a1 = wp * bfpair(pv.y) + a1;
      a2 = wp * bfpair(pv.z) + a2;
      a3 = wp * bfpair(pv.w) + a3;
#endif
    }
  }
  // merge the two corner-pair lanes (tid ^ 4)
  a0.x += __shfl_xor(a0.x, 4); a0.y += __shfl_xor(a0.y, 4);
  a1.x += __shfl_xor(a1.x, 4); a1.y += __shfl_xor(a1.y, 4);
  a2.x += __shfl_xor(a2.x, 4); a2.y += __shfl_xor(a2.y, 4);
  a3.x += __shfl_xor(a3.x, 4); a3.y += __shfl_xor(a3.y, 4);

  if (c2 == 0) {
    uint4 o;
    o.x = (unsigned)f2bf(a0.x) | ((unsigned)f2bf(a0.y) << 16);
    o.y = (unsigned)f2bf(a1.x) | ((unsigned)f2bf(a1.y) << 16);
    o.z = (unsigned)f2bf(a2.x) | ((unsigned)f2bf(a2.y) << 16);
    o.w = (unsigned)f2bf(a3.x) | ((unsigned)f2bf(a3.y) << 16);
    *(uint4*)&xb[qrow * 256 + h * 32 + (dq << 3)] = o;
  }
}

// ---------------------------------------------------------------------------
extern "C" void kernel_launch(void* const* d_in, const int* in_sizes, int n_in,
                              void* d_out, int out_size, void* d_ws,
                              size_t ws_size, hipStream_t stream) {
  (void)in_sizes; (void)n_in; (void)out_size; (void)ws_size;

  const float* query = (const float*)d_in[0];
  const float* refp = (const float*)d_in[1];
  const float* value = (const float*)d_in[2];
  // d_in[3] pad_mask: all-true
  const float* vpk = (const float*)d_in[4];
  const float* vpb = (const float*)d_in[5];
  const float* sok = (const float*)d_in[6];
  const float* sob = (const float*)d_in[7];
  const float* ak = (const float*)d_in[8];
  const float* ab = (const float*)d_in[9];
  const float* okern = (const float*)d_in[10];
  const float* obias = (const float*)d_in[11];

  char* p = (char*)d_ws;
  u16* v_ws = (u16*)p;   p += (size_t)M_ROWS * 256 * 2;   // bf16 vproj
  u16* offaw = (u16*)p;  p += (size_t)M_ROWS * 384 * 2;   // fused off+aw
  u16* qbf = (u16*)p;    p += (size_t)M_ROWS * 256 * 2;   // (aliased by x)
  u16* vbf = (u16*)p;    p += (size_t)M_ROWS * 256 * 2;
  u16* vpk_t = (u16*)p;  p += 65536 * 2;
  u16* sa_t = (u16*)p;   p += 98304 * 2;   // [384][256] = sok_t || ak_t
  u16* ok_t = (u16*)p;   p += 65536 * 2;
  float* bias_cat = (float*)p;  // 384 floats
  u16* x_b = qbf;  // qbf's last read (batched GEMM) precedes sampler writes

  const dim3 blk(256);
  const int mt = (M_ROWS + 127) / 128;  // 287

  cast_qv_k<<<dim3(2350080 / 256), blk, 0, stream>>>(query, value, qbf, vbf);
  wcast_k<<<dim3(898), blk, 0, stream>>>(vpk, sok, ak, okern, sob, ab, vpk_t,
                                         sa_t, ok_t, bias_cat);
  // batched: {v = value@vpk (mode1, bf16 vproj)} + {offaw = query@[sok;ak]}
  gemm_mfma_k<<<dim3(2 * mt + 3 * mt), blk, 0, stream>>>(
      vbf, vpk_t, vpb, v_ws, 256, 2, 1, 2 * mt,
      qbf, sa_t, bias_cat, offaw, 384, 3, 2);
  // softmax + bilinear sampling -> bf16 x
  sampler_k<<<dim3(NTASK / 32), blk, 0, stream>>>(v_ws, offaw, refp, x_b);
  // out = x @ okern + obias (single sub-GEMM)
  gemm_mfma_k<<<dim3(2 * mt), blk, 0, stream>>>(
      x_b, ok_t, obias, (float*)d_out, 256, 2, 0, 2 * mt,
      x_b, ok_t, obias, (float*)d_out, 256, 2, 0);
}